// Round 4
// baseline (505.939 us; speedup 1.0000x reference)
//
#include <hip/hip_runtime.h>
#include <stdint.h>

typedef __attribute__((ext_vector_type(4))) int v4i;

#define BATCH 8192
#define KDIM  4096
#define NOUT  4096
#define KT    (KDIM / 64)   // 64 k-tiles of 64 bytes

// pack_x: f32 row-major -> i8 {1,0} in MFMA tile layout [M/16][K/64][16][64].
// Tile inner byte (m,k) at m*64+k; one thread packs 16 elems (one 16B chunk).
__global__ __launch_bounds__(256) void pack_x(const float* __restrict__ x,
                                              int8_t* __restrict__ xb) {
    size_t t = (size_t)blockIdx.x * 256 + threadIdx.x;
    int row = (int)(t >> 8);              // 256 16-elem chunks per row
    int c   = (int)(t & 255);
    const float4* xp = (const float4*)(x + (size_t)row * KDIM + c * 16);
    uint32_t o[4];
    #pragma unroll
    for (int i = 0; i < 4; ++i) {
        float4 f = xp[i];
        o[i] = (f.x > 0.f ? 1u : 0u) | ((f.y > 0.f ? 1u : 0u) << 8)
             | ((f.z > 0.f ? 1u : 0u) << 16) | ((f.w > 0.f ? 1u : 0u) << 24);
    }
    size_t tile = (size_t)(row >> 4) * KT + (c >> 2);
    *(uint4*)(xb + tile * 1024 + (row & 15) * 64 + (c & 3) * 16) =
        make_uint4(o[0], o[1], o[2], o[3]);
}

// pack_w: f32 row-major -> i8 {+1,-1} in MFMA tile layout [N/16][K/64][16][64].
__global__ __launch_bounds__(256) void pack_w(const float* __restrict__ w,
                                              int8_t* __restrict__ wb) {
    size_t t = (size_t)blockIdx.x * 256 + threadIdx.x;
    int row = (int)(t >> 8);
    int c   = (int)(t & 255);
    const float4* wp = (const float4*)(w + (size_t)row * KDIM + c * 16);
    uint32_t o[4];
    #pragma unroll
    for (int i = 0; i < 4; ++i) {
        float4 f = wp[i];
        o[i] = (f.x > 0.f ? 0x01u : 0xFFu) | ((f.y > 0.f ? 0x01u : 0xFFu) << 8)
             | ((f.z > 0.f ? 0x01u : 0xFFu) << 16) | ((f.w > 0.f ? 0x01u : 0xFFu) << 24);
    }
    size_t tile = (size_t)(row >> 4) * KT + (c >> 2);
    *(uint4*)(wb + tile * 1024 + (row & 15) * 64 + (c & 3) * 16) =
        make_uint4(o[0], o[1], o[2], o[3]);
}

// C[M,N] = A[M,K] * B[N,K]^T on pre-tiled i8 operands, f32 out (integer-exact).
// R4: NO LDS, NO barriers. Each wave owns a 64x64 C-tile (4x4 accs of
// 16x16x64 i8 MFMA) and streams both operands straight from global memory:
// one aligned 1 KB block per fragment load (lane l -> byte (l&15)*64+(l>>4)*16,
// a pure permutation of l*16 -> perfectly coalesced global_load_dwordx4).
// Ping-pong register prefetch: loads for kt+1 issue before the MFMAs of kt,
// so the compiler emits s_waitcnt vmcnt(N) with loads still in flight --
// no s_barrier means no forced vmcnt(0) drain anywhere in the K-loop.
// Cross-wave operand reuse is served by L1/L2 instead of LDS.
__global__ __launch_bounds__(256) void bin_gemm(const int8_t* __restrict__ A,
                                                const int8_t* __restrict__ B,
                                                float* __restrict__ C) {
    const int tid  = threadIdx.x;
    const int w    = tid >> 6;
    const int lane = tid & 63;
    const int q    = lane >> 4;
    const int mp   = lane & 15;

    const int Mt = blockIdx.y * 8 + (w >> 1) * 4;   // 16-row tile index
    const int Nt = blockIdx.x * 8 + (w & 1) * 4;
    const int lo = mp * 64 + q * 16;                // lane offset within 1KB tile

    const int8_t* Ap[4];
    const int8_t* Bp[4];
    #pragma unroll
    for (int i = 0; i < 4; ++i) {
        Ap[i] = A + (size_t)(Mt + i) * KT * 1024 + lo;
        Bp[i] = B + (size_t)(Nt + i) * KT * 1024 + lo;
    }

    v4i a0[4], b0[4], a1[4], b1[4];
    v4i acc[4][4] = {};

    #pragma unroll
    for (int i = 0; i < 4; ++i) {
        a0[i] = *(const v4i*)(Ap[i]);
        b0[i] = *(const v4i*)(Bp[i]);
    }

    for (int kt = 0; kt < KT; kt += 2) {
        const size_t o1 = (size_t)(kt + 1) * 1024;
        #pragma unroll
        for (int i = 0; i < 4; ++i) {
            a1[i] = *(const v4i*)(Ap[i] + o1);
            b1[i] = *(const v4i*)(Bp[i] + o1);
        }
        #pragma unroll
        for (int mi = 0; mi < 4; ++mi)
            #pragma unroll
            for (int ni = 0; ni < 4; ++ni)
                acc[mi][ni] = __builtin_amdgcn_mfma_i32_16x16x64_i8(
                    a0[mi], b0[ni], acc[mi][ni], 0, 0, 0);

        const size_t o2 = (size_t)((kt + 2) & (KT - 1)) * 1024;  // wrap: harmless
        #pragma unroll
        for (int i = 0; i < 4; ++i) {
            a0[i] = *(const v4i*)(Ap[i] + o2);
            b0[i] = *(const v4i*)(Bp[i] + o2);
        }
        #pragma unroll
        for (int mi = 0; mi < 4; ++mi)
            #pragma unroll
            for (int ni = 0; ni < 4; ++ni)
                acc[mi][ni] = __builtin_amdgcn_mfma_i32_16x16x64_i8(
                    a1[mi], b1[ni], acc[mi][ni], 0, 0, 0);
    }

    // C/D layout: col = lane&15, row = quad*4 + reg (verified absmax 0 in R1-3).
    float* Cp = C + (size_t)(Mt * 16 + q * 4) * NOUT + Nt * 16 + mp;
    #pragma unroll
    for (int mi = 0; mi < 4; ++mi)
        #pragma unroll
        for (int ni = 0; ni < 4; ++ni)
            #pragma unroll
            for (int r = 0; r < 4; ++r)
                Cp[(size_t)(mi * 16 + r) * NOUT + ni * 16] = (float)acc[mi][ni][r];
}

extern "C" void kernel_launch(void* const* d_in, const int* in_sizes, int n_in,
                              void* d_out, int out_size, void* d_ws, size_t ws_size,
                              hipStream_t stream) {
    const float* x = (const float*)d_in[0];   // [8192, 4096] f32
    const float* W = (const float*)d_in[1];   // [4096, 4096] f32, values +/-1
    float* out = (float*)d_out;               // [8192, 4096] f32

    int8_t* xb = (int8_t*)d_ws;                           // 32 MiB (tiled)
    int8_t* wb = (int8_t*)d_ws + (size_t)BATCH * KDIM;    // 16 MiB (48 MiB ws total)

    pack_x<<<(BATCH * (size_t)KDIM / 16) / 256, 256, 0, stream>>>(x, xb);
    pack_w<<<((size_t)NOUT * KDIM / 16) / 256, 256, 0, stream>>>(W, wb);

    dim3 grid(NOUT / 128, BATCH / 128);   // (32, 64) = 2048 blocks, 4 waves each
    bin_gemm<<<grid, 256, 0, stream>>>(xb, wb, out);
}

// Round 5
// 441.276 us; speedup vs baseline: 1.1465x; 1.1465x over previous
//
#include <hip/hip_runtime.h>
#include <stdint.h>

typedef __attribute__((ext_vector_type(4))) int v4i;

#define BATCH 8192
#define KDIM  4096
#define NOUT  4096

// pack x: fp32 -> i8 {1,0}, 16 elems/thread, 16B stores (row-major)
__global__ __launch_bounds__(256) void pack_x(const float* __restrict__ x,
                                              uint4* __restrict__ xb) {
    size_t t = (size_t)blockIdx.x * 256 + threadIdx.x;
    const float4* xp = (const float4*)x + t * 4;
    uint32_t o[4];
    #pragma unroll
    for (int i = 0; i < 4; ++i) {
        float4 f = xp[i];
        o[i] = (f.x > 0.f ? 1u : 0u)
             | ((f.y > 0.f ? 1u : 0u) << 8)
             | ((f.z > 0.f ? 1u : 0u) << 16)
             | ((f.w > 0.f ? 1u : 0u) << 24);
    }
    xb[t] = make_uint4(o[0], o[1], o[2], o[3]);
}

// pack W: fp32 -> i8 {+1,-1}, 16 elems/thread, 16B stores (row-major)
__global__ __launch_bounds__(256) void pack_w(const float* __restrict__ w,
                                              uint4* __restrict__ wb) {
    size_t t = (size_t)blockIdx.x * 256 + threadIdx.x;
    const float4* wp = (const float4*)w + t * 4;
    uint32_t o[4];
    #pragma unroll
    for (int i = 0; i < 4; ++i) {
        float4 f = wp[i];
        o[i] = (f.x > 0.f ? 0x01u : 0xFFu)
             | ((f.y > 0.f ? 0x01u : 0xFFu) << 8)
             | ((f.z > 0.f ? 0x01u : 0xFFu) << 16)
             | ((f.w > 0.f ? 0x01u : 0xFFu) << 24);
    }
    wb[t] = make_uint4(o[0], o[1], o[2], o[3]);
}

// C[M,N] = A[M,K] * B[N,K]^T, i8 in, f32 out (integer-exact).
// R5: register-staged LDS pipeline (the hipBLASLt/AITER data path).
//   iter kt: global_load(kt+1)->regs ; ds_read+MFMA on buf[kt&1] ;
//            ds_write regs->buf[(kt+1)&1] (auto vmcnt wait lands AFTER the
//            MFMA phase, so the loads are in flight across all compute) ;
//            __syncthreads (its vmcnt(0) drain is free: loads just consumed).
// Replaces global_load_lds (measured ~21 B/cyc/CU plateau in R1/R2, and the
// same ~22 B/cyc back-computed for m97 bf16 -- the path itself was the wall).
// Staging: thread t covers rows t>>2 and t>>2+64, 16B chunk t&3; LDS chunk
// swizzle c^((r>>1)&3) (R1-verified: 0 bank conflicts). Fragment reads and
// C/D layout unchanged (absmax 0 since R1).
__global__ __launch_bounds__(256) void bin_gemm(const int8_t* __restrict__ A,
                                                const int8_t* __restrict__ B,
                                                float* __restrict__ C) {
    __shared__ __align__(16) int8_t smA[2][128 * 64];
    __shared__ __align__(16) int8_t smB[2][128 * 64];

    const int tid  = threadIdx.x;
    const int w    = tid >> 6;
    const int lane = tid & 63;
    const int q    = lane >> 4;
    const int mp   = lane & 15;

    const int Mbase = blockIdx.y * 128;
    const int Nbase = blockIdx.x * 128;
    const int wm = (w >> 1) * 64;
    const int wn = (w & 1) * 64;

    // staging coordinates
    const int c  = tid & 3;
    const int r0 = tid >> 2;        // 0..63
    const int r1 = r0 + 64;         // 64..127

    const int8_t* gA0 = A + (size_t)(Mbase + r0) * KDIM + c * 16;
    const int8_t* gA1 = A + (size_t)(Mbase + r1) * KDIM + c * 16;
    const int8_t* gB0 = B + (size_t)(Nbase + r0) * KDIM + c * 16;
    const int8_t* gB1 = B + (size_t)(Nbase + r1) * KDIM + c * 16;

    const int lo0 = r0 * 64 + ((c ^ ((r0 >> 1) & 3)) * 16);
    const int lo1 = r1 * 64 + ((c ^ ((r1 >> 1) & 3)) * 16);

    const int slot = (q ^ ((mp >> 1) & 3)) * 16;

    v4i acc[4][4] = {};
    v4i ra0, ra1, rb0, rb1;

    // prologue: tile 0 -> buf 0
    ra0 = *(const v4i*)(gA0); ra1 = *(const v4i*)(gA1);
    rb0 = *(const v4i*)(gB0); rb1 = *(const v4i*)(gB1);
    *(v4i*)(&smA[0][lo0]) = ra0; *(v4i*)(&smA[0][lo1]) = ra1;
    *(v4i*)(&smB[0][lo0]) = rb0; *(v4i*)(&smB[0][lo1]) = rb1;
    __syncthreads();

    #define COMPUTE(BUF)                                                        \
        {                                                                       \
            v4i af[4], bf[4];                                                   \
            _Pragma("unroll")                                                   \
            for (int i = 0; i < 4; ++i)                                         \
                af[i] = *(const v4i*)(&smA[BUF][(wm + i * 16 + mp) * 64 + slot]);\
            _Pragma("unroll")                                                   \
            for (int i = 0; i < 4; ++i)                                         \
                bf[i] = *(const v4i*)(&smB[BUF][(wn + i * 16 + mp) * 64 + slot]);\
            _Pragma("unroll")                                                   \
            for (int mi = 0; mi < 4; ++mi)                                      \
                _Pragma("unroll")                                               \
                for (int ni = 0; ni < 4; ++ni)                                  \
                    acc[mi][ni] = __builtin_amdgcn_mfma_i32_16x16x64_i8(        \
                        af[mi], bf[ni], acc[mi][ni], 0, 0, 0);                  \
        }

    for (int kt = 0; kt < KDIM / 64; kt += 2) {
        // --- step A: compute buf0, prefetch tile kt+1 -> buf1 ---
        {
            const int ko = (kt + 1) * 64;
            ra0 = *(const v4i*)(gA0 + ko); ra1 = *(const v4i*)(gA1 + ko);
            rb0 = *(const v4i*)(gB0 + ko); rb1 = *(const v4i*)(gB1 + ko);
        }
        COMPUTE(0)
        *(v4i*)(&smA[1][lo0]) = ra0; *(v4i*)(&smA[1][lo1]) = ra1;
        *(v4i*)(&smB[1][lo0]) = rb0; *(v4i*)(&smB[1][lo1]) = rb1;
        __syncthreads();

        // --- step B: compute buf1, prefetch tile (kt+2)&63 -> buf0 ---
        {
            const int ko = ((kt + 2) & 63) * 64;   // last iter: harmless reload of tile 0
            ra0 = *(const v4i*)(gA0 + ko); ra1 = *(const v4i*)(gA1 + ko);
            rb0 = *(const v4i*)(gB0 + ko); rb1 = *(const v4i*)(gB1 + ko);
        }
        COMPUTE(1)
        *(v4i*)(&smA[0][lo0]) = ra0; *(v4i*)(&smA[0][lo1]) = ra1;
        *(v4i*)(&smB[0][lo0]) = rb0; *(v4i*)(&smB[0][lo1]) = rb1;
        __syncthreads();
    }
    #undef COMPUTE

    // C/D layout: col = lane&15, row = quad*4 + reg (verified absmax 0, R1-4).
    float* Cp = C + (size_t)(Mbase + wm + q * 4) * NOUT + (Nbase + wn + mp);
    #pragma unroll
    for (int mi = 0; mi < 4; ++mi)
        #pragma unroll
        for (int ni = 0; ni < 4; ++ni)
            #pragma unroll
            for (int r = 0; r < 4; ++r)
                Cp[(size_t)(mi * 16 + r) * NOUT + ni * 16] = (float)acc[mi][ni][r];
}

extern "C" void kernel_launch(void* const* d_in, const int* in_sizes, int n_in,
                              void* d_out, int out_size, void* d_ws, size_t ws_size,
                              hipStream_t stream) {
    const float* x = (const float*)d_in[0];   // [8192, 4096] f32
    const float* W = (const float*)d_in[1];   // [4096, 4096] f32, values +/-1
    float* out = (float*)d_out;               // [8192, 4096] f32

    int8_t* xb = (int8_t*)d_ws;                           // 32 MiB
    int8_t* wb = (int8_t*)d_ws + (size_t)BATCH * KDIM;    // 16 MiB (48 MiB ws total)

    pack_x<<<(BATCH * (size_t)KDIM / 16) / 256, 256, 0, stream>>>(x, (uint4*)xb);
    pack_w<<<((size_t)NOUT * KDIM / 16) / 256, 256, 0, stream>>>(W, (uint4*)wb);

    dim3 grid(NOUT / 128, BATCH / 128);   // (32, 64) = 2048 blocks
    bin_gemm<<<grid, 256, 0, stream>>>(xb, wb, out);
}